// Round 2
// baseline (100.420 us; speedup 1.0000x reference)
//
#include <hip/hip_runtime.h>

#define NODES 10000
#define ROWS  20000          // NODES * B, row r = n*2 + b, 64 features per row

// ---------------------------------------------------------------------------
// Kernel 1 — projection, hoisted out of the per-node gather:
//   Y[r][o] = sum_k x[r][k] * W[o][k]        (k<64, Wa half)   -> bf16 table
//   S[r][o] = sum_k x[r][k] * W[o][64+k] + b (Ws half + bias)  -> f32 table
// lane = o. Each lane keeps its whole W row (128 f32) in VGPRs; x[r][k] is
// broadcast with v_readlane (SALU, co-issues with the FMAs).
// ---------------------------------------------------------------------------
__launch_bounds__(256, 2)
__global__ void pgnn_proj(const float* __restrict__ x,
                          const float* __restrict__ W,
                          const float* __restrict__ bias,
                          unsigned short* __restrict__ Yb,
                          float* __restrict__ S,
                          int nWaves) {
    const int lane = threadIdx.x & 63;
    const int wid  = (blockIdx.x * blockDim.x + threadIdx.x) >> 6;

    float wreg[128];
    {
        const float4* wr = reinterpret_cast<const float4*>(W + lane * 128);
        #pragma unroll
        for (int q = 0; q < 32; ++q) {
            float4 v = wr[q];
            wreg[q * 4 + 0] = v.x; wreg[q * 4 + 1] = v.y;
            wreg[q * 4 + 2] = v.z; wreg[q * 4 + 3] = v.w;
        }
    }
    const float bl = bias[lane];

    int r = wid;
    if (r >= ROWS) return;
    float xv = x[r * 64 + lane];
    while (true) {
        const int rn = r + nWaves;
        float xnext = 0.f;
        if (rn < ROWS) xnext = x[rn * 64 + lane];   // prefetch next row

        float acc0 = 0.f, acc1 = bl;
        #pragma unroll
        for (int k = 0; k < 64; ++k) {
            float sx = __uint_as_float(
                __builtin_amdgcn_readlane(__float_as_uint(xv), k));
            acc0 = fmaf(sx, wreg[k],      acc0);   // Wa -> Y
            acc1 = fmaf(sx, wreg[64 + k], acc1);   // Ws -> S
        }
        // Y as bf16 (RNE)
        unsigned u = __float_as_uint(acc0);
        u += 0x7FFFu + ((u >> 16) & 1u);
        Yb[r * 64 + lane] = (unsigned short)(u >> 16);
        S [r * 64 + lane] = acc1;

        if (rn >= ROWS) break;
        r = rn; xv = xnext;
    }
}

// ---------------------------------------------------------------------------
// Kernel 2 — gather on projected values. One wave per node, no LDS:
//   out[n][j] = (1/64) * sum_a d[n,a] * Y[idx[n,a]][j] + S[n][j]
// lane covers j = 2*lane, 2*lane+1 (one dword of the 256B bf16 Y row).
// ---------------------------------------------------------------------------
__launch_bounds__(256, 4)
__global__ void pgnn_gather(const float* __restrict__ dmax,
                            const int*   __restrict__ amax,
                            const unsigned short* __restrict__ Yb,
                            const float* __restrict__ S,
                            float*       __restrict__ out) {
    const int lane = threadIdx.x & 63;
    const int n    = (blockIdx.x * blockDim.x + threadIdx.x) >> 6;
    if (n >= NODES) return;

    const float dv = dmax[n * 64 + lane];
    const int   iv = amax[n * 64 + lane];

    float a0 = 0.f, a1 = 0.f;
    #pragma unroll 16
    for (int a = 0; a < 64; ++a) {
        const int   m  = __builtin_amdgcn_readlane(iv, a);
        const float dd = __uint_as_float(
            __builtin_amdgcn_readlane(__float_as_uint(dv), a));
        const unsigned yv =
            *reinterpret_cast<const unsigned*>(Yb + m * 128 + lane * 2);
        a0 = fmaf(dd, __uint_as_float(yv << 16),          a0);
        a1 = fmaf(dd, __uint_as_float(yv & 0xFFFF0000u), a1);
    }

    const float2 sv = *reinterpret_cast<const float2*>(S + n * 128 + lane * 2);
    float2 o2;
    o2.x = a0 * (1.0f / 64.0f) + sv.x;
    o2.y = a1 * (1.0f / 64.0f) + sv.y;
    *reinterpret_cast<float2*>(out + n * 128 + lane * 2) = o2;
}

extern "C" void kernel_launch(void* const* d_in, const int* in_sizes, int n_in,
                              void* d_out, int out_size, void* d_ws, size_t ws_size,
                              hipStream_t stream) {
    const float* x    = (const float*)d_in[0];   // (10000, 2, 64)
    const float* dm   = (const float*)d_in[1];   // (10000, 64)
    const int*   am   = (const int*)  d_in[2];   // (10000, 64)
    const float* W    = (const float*)d_in[3];   // (64, 128)
    const float* bias = (const float*)d_in[4];   // (64,)
    float* out = (float*)d_out;                  // (10000, 2, 64)

    unsigned short* Yb = (unsigned short*)d_ws;                    // 2.56 MB bf16
    float*          S  = (float*)((char*)d_ws + (4u << 20));       // 5.12 MB f32

    const int projBlocks = 320;                  // 1280 waves, ~15.6 rows each
    pgnn_proj<<<projBlocks, 256, 0, stream>>>(x, W, bias, Yb, S, projBlocks * 4);

    const int gatherBlocks = (NODES + 3) / 4;    // one wave per node
    pgnn_gather<<<gatherBlocks, 256, 0, stream>>>(dm, am, Yb, S, out);
}

// Round 3
// 94.283 us; speedup vs baseline: 1.0651x; 1.0651x over previous
//
#include <hip/hip_runtime.h>

#define NODES 10000
#define ROWS  20000          // NODES * B; row r = n*2 + b, 64 floats per row

typedef unsigned short bf16raw;

// ---------------------------------------------------------------------------
// Kernel 1 — projection hoisted out of the gather:
//   Y[r][o] = x[r] . Wa[o]          -> bf16 table (gathered later, 2x less L2)
//   S[r][o] = x[r] . Ws[o] + b[o]   -> f32 table
// lane = o; full W row (128 f32) lives in VGPRs; x broadcast via v_readlane.
// Two rows per iteration -> 4 independent FMA chains (latency-covered);
// 2048 waves -> 2 blocks/CU resident, no serial-chain exposure (round-2 bug).
// ---------------------------------------------------------------------------
__launch_bounds__(256, 2)
__global__ void pgnn_proj(const float* __restrict__ x,
                          const float* __restrict__ W,
                          const float* __restrict__ bias,
                          bf16raw* __restrict__ Yb,
                          float*   __restrict__ S,
                          int nWaves) {
    const int lane = threadIdx.x & 63;
    const int wid  = (blockIdx.x * blockDim.x + threadIdx.x) >> 6;

    float wa[64], ws[64];
    {
        const float4* wr = reinterpret_cast<const float4*>(W + lane * 128);
        #pragma unroll
        for (int q = 0; q < 16; ++q) {
            float4 v = wr[q];
            wa[q*4+0] = v.x; wa[q*4+1] = v.y; wa[q*4+2] = v.z; wa[q*4+3] = v.w;
        }
        #pragma unroll
        for (int q = 0; q < 16; ++q) {
            float4 v = wr[16 + q];
            ws[q*4+0] = v.x; ws[q*4+1] = v.y; ws[q*4+2] = v.z; ws[q*4+3] = v.w;
        }
    }
    const float bl = bias[lane];

    for (int r = wid * 2; r < ROWS; r += nWaves * 2) {
        const float xv0 = x[r * 64 + lane];        // row r
        const float xv1 = x[r * 64 + 64 + lane];   // row r+1
        float y0 = 0.f, s0 = bl, y1 = 0.f, s1 = bl;
        #pragma unroll
        for (int k = 0; k < 64; ++k) {
            const float a0 = __uint_as_float(
                __builtin_amdgcn_readlane(__float_as_uint(xv0), k));
            const float a1 = __uint_as_float(
                __builtin_amdgcn_readlane(__float_as_uint(xv1), k));
            y0 = fmaf(a0, wa[k], y0);
            s0 = fmaf(a0, ws[k], s0);
            y1 = fmaf(a1, wa[k], y1);
            s1 = fmaf(a1, ws[k], s1);
        }
        unsigned u0 = __float_as_uint(y0); u0 += 0x7FFFu + ((u0 >> 16) & 1u);
        unsigned u1 = __float_as_uint(y1); u1 += 0x7FFFu + ((u1 >> 16) & 1u);
        Yb[r * 64 + lane]      = (bf16raw)(u0 >> 16);
        Yb[r * 64 + 64 + lane] = (bf16raw)(u1 >> 16);
        S [r * 64 + lane]      = s0;
        S [r * 64 + 64 + lane] = s1;
    }
}

// ---------------------------------------------------------------------------
// Kernel 2 — gather on projected values. One wave per node, no LDS, no syncs:
//   out[n][j] = (1/64) * sum_a d[n,a] * Y[idx[n,a]][j] + S[n][j]
// lane covers j = 2*lane, 2*lane+1 (one dword of the 256 B bf16 Y row-pair).
// ---------------------------------------------------------------------------
__launch_bounds__(256, 4)
__global__ void pgnn_gather(const float* __restrict__ dmax,
                            const int*   __restrict__ amax,
                            const bf16raw* __restrict__ Yb,
                            const float* __restrict__ S,
                            float*       __restrict__ out) {
    const int lane = threadIdx.x & 63;
    const int n    = (blockIdx.x * blockDim.x + threadIdx.x) >> 6;
    if (n >= NODES) return;

    const float dv = dmax[n * 64 + lane];
    const int   iv = amax[n * 64 + lane];
    const float2 sv = *reinterpret_cast<const float2*>(S + n * 128 + lane * 2);

    float a0 = 0.f, a1 = 0.f;
    #pragma unroll 16
    for (int a = 0; a < 64; ++a) {
        const int   m  = __builtin_amdgcn_readlane(iv, a);
        const float dd = __uint_as_float(
            __builtin_amdgcn_readlane(__float_as_uint(dv), a));
        const unsigned yv =
            *reinterpret_cast<const unsigned*>(Yb + m * 128 + lane * 2);
        a0 = fmaf(dd, __uint_as_float(yv << 16),          a0);
        a1 = fmaf(dd, __uint_as_float(yv & 0xFFFF0000u), a1);
    }

    float2 o2;
    o2.x = fmaf(a0, 1.0f / 64.0f, sv.x);
    o2.y = fmaf(a1, 1.0f / 64.0f, sv.y);
    *reinterpret_cast<float2*>(out + n * 128 + lane * 2) = o2;
}

extern "C" void kernel_launch(void* const* d_in, const int* in_sizes, int n_in,
                              void* d_out, int out_size, void* d_ws, size_t ws_size,
                              hipStream_t stream) {
    const float* x    = (const float*)d_in[0];   // (10000, 2, 64)
    const float* dm   = (const float*)d_in[1];   // (10000, 64)
    const int*   am   = (const int*)  d_in[2];   // (10000, 64)
    const float* W    = (const float*)d_in[3];   // (64, 128)
    const float* bias = (const float*)d_in[4];   // (64,)
    float* out = (float*)d_out;                  // (10000, 2, 64)

    bf16raw* Yb = (bf16raw*)d_ws;                            // 2.56 MB bf16
    float*   S  = (float*)((char*)d_ws + (4u << 20));        // 5.12 MB f32

    const int projBlocks = 512;                  // 2048 waves, 2 blocks/CU
    pgnn_proj<<<projBlocks, 256, 0, stream>>>(x, W, bias, Yb, S, projBlocks * 4);

    const int gatherBlocks = (NODES + 3) / 4;    // one wave per node
    pgnn_gather<<<gatherBlocks, 256, 0, stream>>>(dm, am, Yb, S, out);
}